// Round 14
// baseline (119.586 us; speedup 1.0000x reference)
//
#include <hip/hip_runtime.h>

typedef __bf16 bf16;
typedef __attribute__((ext_vector_type(4))) bf16 bf16x4;
typedef __attribute__((ext_vector_type(8))) bf16 bf16x8;
typedef __attribute__((ext_vector_type(4))) float f32x4;

namespace {

constexpr int NITERS = 50;   // R11 ERRATUM: slowest mode contracts ~0.95/iter;
                             // ref's 50-iter iterate is NOT the fixed point ->
                             // iteration count must match exactly.

// ---- compile-time physical constants (double) ----
constexpr double csqrt(double x) {
  double s = x > 1 ? x : 1;
  for (int i = 0; i < 60; ++i) s = 0.5 * (s + x / s);
  return s;
}
constexpr double AP_D =
    ((3.667 - 1.0) / (3.667 + 0.5)) * (0.3 * (7.5 * csqrt(7.5)) / 0.0002395);
constexpr double RGAST_D = (8.3144598 / 4184.0) * 623.15;

__device__ __forceinline__ float sss_val(int i, int j) {
  // SSS[i][j] = exp(-DELTAW/(RGAS*T)); symmetric; zero outside 51x51 (pad)
  if (i > 50 || j > 50) return 0.0f;
  const float si = -0.025f + 0.001f * (float)i;
  const float sj = -0.025f + 0.001f * (float)j;
  const float acc = fmaxf(0.0f, fmaxf(si, sj) - 0.0084f);
  const float don = fminf(0.0f, fminf(si, sj) + 0.0084f);
  const float dw = (float)(AP_D * 0.5) * (si + sj) * (si + sj) + 85580.0f * acc * don;
  return expf(-dw * (float)(1.0 / RGAST_D));
}

__device__ __forceinline__ float fast_log(float x) {
  return __builtin_amdgcn_logf(x) * 0.69314718056f;   // ln via log2
}

// HW-verified gfx950 shape (guide §3; R4/R5/R8/R9 passed with it).
__device__ __forceinline__ f32x4 mfma(bf16x8 a, bf16x8 b, f32x4 c) {
  return __builtin_amdgcn_mfma_f32_16x16x32_bf16(a, b, c, 0, 0, 0);
}

} // namespace

// One wave = 16 solves (8 elements x {pure, mix}); zero cross-lane movement
// in the hot loop: k-dim of S permuted by sigma(32kt+8g+i) =
// 16*(2kt+(i>>2)) + 4g + (i&3), so lane (s,g)'s B fragment is its own
// C-layout Gt values (R9). State Gt = w (.) G; Gt' = 0.5*(Gt + w*rcp(d)).
// R14: the two k-MFMAs per tile accumulate into INDEPENDENT accumulators
// (accA from b0, accB from b1; summed by VALU) -- all 8 MFMAs/iter are
// mutually independent, cutting one MFMA latency (~32 cyc) off the serial
// chain that R9-R13 showed is the wall (stalls, not issue, dominate).
// Conversion Gt->bf16: plain casts + shufflevector (R10/R13: alternatives
// neutral-to-worse). Pads: S rows/cols >=51 are 0; pad out-rows get +1 via
// accA[3]'s init C operand, w=0 there -> Gt stays 0.
__global__ __launch_bounds__(256, 4) void cosmo_mfma_sp(
    const float* __restrict__ my_sigma,   // [B,51]
    const float* __restrict__ v_comp,     // [B]
    const float* __restrict__ vt_sigma,   // [B,51,2]
    const float* __restrict__ v_vt,       // [B]
    float* __restrict__ out,              // [B]
    int B)
{
  const int lane = threadIdx.x & 63;
  const int wv   = threadIdx.x >> 6;
  const int s    = lane & 15;     // solve slot (C col / A-frag m pos)
  const int g    = lane >> 4;     // lane group 0..3
  const int e    = blockIdx.x * 32 + wv * 8 + (s >> 1);
  const int task = s & 1;         // 0 = pure, 1 = mix
  const bool ein = (e < B);
  const int  ec  = ein ? e : 0;

  // ---- rows owned by this lane in C layout: n = 16t + 4g + r ----
  float A0, A1, wC[16];
  {
    float myv[16], vtv[16];
#pragma unroll
    for (int t = 0; t < 4; ++t)
#pragma unroll
      for (int r = 0; r < 4; ++r) {
        const int n  = 16 * t + 4 * g + r;
        const bool nv = (n < 51) && ein;
        const int nc = (n < 51) ? n : 50;
        myv[4 * t + r] = nv ? my_sigma[(size_t)ec * 51 + nc] : 0.0f;
        vtv[4 * t + r] = nv ? vt_sigma[((size_t)ec * 51 + nc) * 2 + 1] : 0.0f;
      }
    float pA0 = 0.f, pA1 = 0.f;
#pragma unroll
    for (int i = 0; i < 16; ++i) { pA0 += myv[i]; pA1 += vtv[i]; }
    A0 = pA0; A0 += __shfl_xor(A0, 16, 64); A0 += __shfl_xor(A0, 32, 64);
    A1 = pA1; A1 += __shfl_xor(A1, 16, 64); A1 += __shfl_xor(A1, 32, 64);

    const float den  = task ? (0.235f * A0 + 0.765f * A1) : A0;
    const float rden = __builtin_amdgcn_rcpf(den);
#pragma unroll
    for (int i = 0; i < 16; ++i) {
      const float num = task ? (0.235f * myv[i] + 0.765f * vtv[i]) : myv[i];
      wC[i] = num * rden;     // psigma of this task; 0 on pads
    }
  }

  float Gt[16];                   // state: Gt = w * G, init G = 1
#pragma unroll
  for (int i = 0; i < 16; ++i) Gt[i] = wC[i];

  // ---- constant A fragments with permuted k:
  //      afr[tp][kt][i] = S[16tp + s][ 16*(2kt + (i>>2)) + 4g + (i&3) ] ----
  bf16x8 afr[4][2];
#pragma unroll
  for (int tp = 0; tp < 4; ++tp)
#pragma unroll
    for (int kt = 0; kt < 2; ++kt) {
      bf16x8 v;
#pragma unroll
      for (int i = 0; i < 8; ++i) {
        const int n_src = 16 * (2 * kt + (i >> 2)) + 4 * g + (i & 3);
        v[i] = (bf16)sss_val(16 * tp + s, n_src);
      }
      afr[tp][kt] = v;
    }

  // tile-3 pad indicator folded into accA[3]'s init (C operand):
  // n_out = 48 + 4g + r >= 51  ->  d starts at 1, w=0 -> Gt stays 0.
  f32x4 pad3;
#pragma unroll
  for (int r = 0; r < 4; ++r) pad3[r] = (4 * g + r >= 3) ? 1.0f : 0.0f;

  // ---- 50-step damped fixed point: zero DS ops, zero shuffles ----
#pragma unroll 1
  for (int it = 0; it < NITERS; ++it) {
    bf16x4 hb[4];
#pragma unroll
    for (int t = 0; t < 4; ++t)
#pragma unroll
      for (int r = 0; r < 4; ++r)
        hb[t][r] = (bf16)Gt[4 * t + r];

    const bf16x8 b0 = __builtin_shufflevector(hb[0], hb[1], 0, 1, 2, 3, 4, 5, 6, 7);
    const bf16x8 b1 = __builtin_shufflevector(hb[2], hb[3], 0, 1, 2, 3, 4, 5, 6, 7);

    const f32x4 z = {};
    f32x4 accA[4], accB[4];       // independent: no MFMA->MFMA dependency
#pragma unroll
    for (int tp = 0; tp < 3; ++tp) accA[tp] = mfma(afr[tp][0], b0, z);
    accA[3] = mfma(afr[3][0], b0, pad3);
#pragma unroll
    for (int tp = 0; tp < 4; ++tp) accB[tp] = mfma(afr[tp][1], b1, z);

    // Gt <- 0.5*(Gt + w*rcp(accA+accB))
#pragma unroll
    for (int tp = 0; tp < 4; ++tp)
#pragma unroll
      for (int r = 0; r < 4; ++r) {
        const int i = 4 * tp + r;
        const float d  = accA[tp][r] + accB[tp][r];
        const float rc = __builtin_amdgcn_rcpf(d);
        Gt[i] = 0.5f * __builtin_fmaf(wC[i], rc, Gt[i]);
      }
  }

  // ---- epilogue: S_task = sum_n psigma_pure[n] * ln(G[n]), G = Gt/w ----
  const float rA0 = __builtin_amdgcn_rcpf(A0);
  float Sp = 0.f;
#pragma unroll
  for (int t = 0; t < 4; ++t)
#pragma unroll
    for (int r = 0; r < 4; ++r) {
      const int n = 16 * t + 4 * g + r;
      if (n < 51) {
        const int i = 4 * t + r;
        const float p  = (ein ? my_sigma[(size_t)ec * 51 + n] : 0.0f) * rA0;
        // guard wC==0 (exact-0 input): p==0 there, force ln arg -> 1
        const float gg = (wC[i] != 0.0f)
                           ? Gt[i] * __builtin_amdgcn_rcpf(wC[i]) : 1.0f;
        Sp += p * __builtin_amdgcn_logf(gg);
      }
    }
  Sp += __shfl_xor(Sp, 16, 64);
  Sp += __shfl_xor(Sp, 32, 64);
  const float St = Sp * 0.69314718056f;
  const float So = __shfl_xor(St, 1, 64);   // partner task's sum

  if (task == 0 && g == 0 && ein) {
    const float lng_resid = A0 * (1.0f / 7.5f) * (So - St);
    const float v0  = v_comp[e];
    const float v1v = v_vt[e];
    const float q0 = A0 * (1.0f / 79.53f), q1 = A1 * (1.0f / 79.53f);
    const float r0 = v0 * (1.0f / 66.69f), r1 = v1v * (1.0f / 66.69f);
    const float xq = 0.235f * q0 + 0.765f * q1;
    const float xr = 0.235f * r0 + 0.765f * r1;
    const float theta = 0.235f * q0 * __builtin_amdgcn_rcpf(xq);
    const float phi   = 0.235f * r0 * __builtin_amdgcn_rcpf(xr);
    const float l0 = 5.0f * (r0 - q0) - (r0 - 1.0f);
    const float l1 = 5.0f * (r1 - q1) - (r1 - 1.0f);
    const float xl = 0.235f * l0 + 0.765f * l1;
    const float lng_comb = fast_log(phi * (1.0f / 0.235f))
                         + 5.0f * q0 * fast_log(theta * __builtin_amdgcn_rcpf(phi))
                         + l0 - (phi * (1.0f / 0.235f)) * xl;
    out[e] = lng_resid + lng_comb;
  }
}

extern "C" void kernel_launch(void* const* d_in, const int* in_sizes, int n_in,
                              void* d_out, int out_size, void* d_ws, size_t ws_size,
                              hipStream_t stream) {
  const float* my  = (const float*)d_in[0];
  const float* vc  = (const float*)d_in[1];
  const float* vts = (const float*)d_in[2];
  const float* vvt = (const float*)d_in[3];
  float* out = (float*)d_out;
  const int B = in_sizes[1];                    // v_compound is [B]
  const int grid = (B + 31) / 32;               // 32 elements per 256-thread block
  cosmo_mfma_sp<<<grid, 256, 0, stream>>>(my, vc, vts, vvt, out, B);
}

// Round 15
// 118.075 us; speedup vs baseline: 1.0128x; 1.0128x over previous
//
#include <hip/hip_runtime.h>

typedef __bf16 bf16;
typedef __attribute__((ext_vector_type(4))) bf16 bf16x4;
typedef __attribute__((ext_vector_type(8))) bf16 bf16x8;
typedef __attribute__((ext_vector_type(4))) float f32x4;

namespace {

constexpr int NITERS = 50;   // R11 ERRATUM: slowest mode contracts ~0.95/iter;
                             // ref's 50-iter iterate is NOT the fixed point ->
                             // iteration count must match exactly.

// ---- compile-time physical constants (double) ----
constexpr double csqrt(double x) {
  double s = x > 1 ? x : 1;
  for (int i = 0; i < 60; ++i) s = 0.5 * (s + x / s);
  return s;
}
constexpr double AP_D =
    ((3.667 - 1.0) / (3.667 + 0.5)) * (0.3 * (7.5 * csqrt(7.5)) / 0.0002395);
constexpr double RGAST_D = (8.3144598 / 4184.0) * 623.15;

__device__ __forceinline__ float sss_val(int i, int j) {
  // SSS[i][j] = exp(-DELTAW/(RGAS*T)); symmetric; zero outside 51x51 (pad)
  if (i > 50 || j > 50) return 0.0f;
  const float si = -0.025f + 0.001f * (float)i;
  const float sj = -0.025f + 0.001f * (float)j;
  const float acc = fmaxf(0.0f, fmaxf(si, sj) - 0.0084f);
  const float don = fminf(0.0f, fminf(si, sj) + 0.0084f);
  const float dw = (float)(AP_D * 0.5) * (si + sj) * (si + sj) + 85580.0f * acc * don;
  return expf(-dw * (float)(1.0 / RGAST_D));
}

__device__ __forceinline__ float fast_log(float x) {
  return __builtin_amdgcn_logf(x) * 0.69314718056f;   // ln via log2
}

// HW-verified gfx950 shape (guide §3; R4/R5/R8/R9 passed with it).
__device__ __forceinline__ f32x4 mfma(bf16x8 a, bf16x8 b, f32x4 c) {
  return __builtin_amdgcn_mfma_f32_16x16x32_bf16(a, b, c, 0, 0, 0);
}

} // namespace

// One wave = 16 solves (8 elements x {pure, mix}); zero cross-lane movement
// in the hot loop: k-dim of S permuted by sigma(32kt+8g+i) =
// 16*(2kt+(i>>2)) + 4g + (i&3), so lane (s,g)'s B fragment is its own
// C-layout Gt values (R9 structure -- measured best at 57.6 us kernel).
// R15: the 4 waves of a block are PHASE-STAGGERED by s_sleep(2*wv)
// (~128 cyc steps). R9-R14 counters fit a convoy model: identical,
// memory-op-free loops keep all 4 waves/SIMD phase-locked, so every wave
// sits in the MFMA-latency shadow simultaneously (VALUBusy stuck at 68%,
// ~15% of wall un-issuable). A one-time ~1/4-iteration offset per wave
// de-convoys them; the uniform loop preserves the offset.
// State Gt = w (.) G; Gt' = 0.5*(Gt + w*rcp(d)). Pads: S rows/cols >=51 are
// 0; pad out-rows get +1 via acc[3]'s init C operand, w=0 -> Gt stays 0.
__global__ __launch_bounds__(256, 4) void cosmo_mfma_stg(
    const float* __restrict__ my_sigma,   // [B,51]
    const float* __restrict__ v_comp,     // [B]
    const float* __restrict__ vt_sigma,   // [B,51,2]
    const float* __restrict__ v_vt,       // [B]
    float* __restrict__ out,              // [B]
    int B)
{
  const int lane = threadIdx.x & 63;
  const int wv   = threadIdx.x >> 6;
  const int s    = lane & 15;     // solve slot (C col / A-frag m pos)
  const int g    = lane >> 4;     // lane group 0..3
  const int e    = blockIdx.x * 32 + wv * 8 + (s >> 1);
  const int task = s & 1;         // 0 = pure, 1 = mix
  const bool ein = (e < B);
  const int  ec  = ein ? e : 0;

  // ---- rows owned by this lane in C layout: n = 16t + 4g + r ----
  float A0, A1, wC[16];
  {
    float myv[16], vtv[16];
#pragma unroll
    for (int t = 0; t < 4; ++t)
#pragma unroll
      for (int r = 0; r < 4; ++r) {
        const int n  = 16 * t + 4 * g + r;
        const bool nv = (n < 51) && ein;
        const int nc = (n < 51) ? n : 50;
        myv[4 * t + r] = nv ? my_sigma[(size_t)ec * 51 + nc] : 0.0f;
        vtv[4 * t + r] = nv ? vt_sigma[((size_t)ec * 51 + nc) * 2 + 1] : 0.0f;
      }
    float pA0 = 0.f, pA1 = 0.f;
#pragma unroll
    for (int i = 0; i < 16; ++i) { pA0 += myv[i]; pA1 += vtv[i]; }
    A0 = pA0; A0 += __shfl_xor(A0, 16, 64); A0 += __shfl_xor(A0, 32, 64);
    A1 = pA1; A1 += __shfl_xor(A1, 16, 64); A1 += __shfl_xor(A1, 32, 64);

    const float den  = task ? (0.235f * A0 + 0.765f * A1) : A0;
    const float rden = __builtin_amdgcn_rcpf(den);
#pragma unroll
    for (int i = 0; i < 16; ++i) {
      const float num = task ? (0.235f * myv[i] + 0.765f * vtv[i]) : myv[i];
      wC[i] = num * rden;     // psigma of this task; 0 on pads
    }
  }

  float Gt[16];                   // state: Gt = w * G, init G = 1
#pragma unroll
  for (int i = 0; i < 16; ++i) Gt[i] = wC[i];

  // ---- constant A fragments with permuted k:
  //      afr[tp][kt][i] = S[16tp + s][ 16*(2kt + (i>>2)) + 4g + (i&3) ] ----
  bf16x8 afr[4][2];
#pragma unroll
  for (int tp = 0; tp < 4; ++tp)
#pragma unroll
    for (int kt = 0; kt < 2; ++kt) {
      bf16x8 v;
#pragma unroll
      for (int i = 0; i < 8; ++i) {
        const int n_src = 16 * (2 * kt + (i >> 2)) + 4 * g + (i & 3);
        v[i] = (bf16)sss_val(16 * tp + s, n_src);
      }
      afr[tp][kt] = v;
    }

  // tile-3 pad indicator folded into acc[3]'s init (C operand):
  // n_out = 48 + 4g + r >= 51  ->  d starts at 1, w=0 -> Gt stays 0.
  f32x4 pad3;
#pragma unroll
  for (int r = 0; r < 4; ++r) pad3[r] = (4 * g + r >= 3) ? 1.0f : 0.0f;

  // ---- de-convoy the block's 4 waves: ~128-cyc phase steps ----
  switch (wv) {
    case 1: __builtin_amdgcn_s_sleep(2); break;
    case 2: __builtin_amdgcn_s_sleep(4); break;
    case 3: __builtin_amdgcn_s_sleep(6); break;
    default: break;
  }

  // ---- 50-step damped fixed point: zero DS ops, zero shuffles ----
#pragma unroll 1
  for (int it = 0; it < NITERS; ++it) {
    bf16x4 hb[4];
#pragma unroll
    for (int t = 0; t < 4; ++t)
#pragma unroll
      for (int r = 0; r < 4; ++r)
        hb[t][r] = (bf16)Gt[4 * t + r];

    const bf16x8 b0 = __builtin_shufflevector(hb[0], hb[1], 0, 1, 2, 3, 4, 5, 6, 7);
    const bf16x8 b1 = __builtin_shufflevector(hb[2], hb[3], 0, 1, 2, 3, 4, 5, 6, 7);

    const f32x4 z = {};
    f32x4 acc[4];
#pragma unroll
    for (int tp = 0; tp < 3; ++tp) acc[tp] = mfma(afr[tp][0], b0, z);
    acc[3] = mfma(afr[3][0], b0, pad3);
#pragma unroll
    for (int tp = 0; tp < 4; ++tp) acc[tp] = mfma(afr[tp][1], b1, acc[tp]);

    // Gt <- 0.5*(Gt + w*rcp(d))
#pragma unroll
    for (int tp = 0; tp < 4; ++tp)
#pragma unroll
      for (int r = 0; r < 4; ++r) {
        const int i = 4 * tp + r;
        const float rc = __builtin_amdgcn_rcpf(acc[tp][r]);
        Gt[i] = 0.5f * __builtin_fmaf(wC[i], rc, Gt[i]);
      }
  }

  // ---- epilogue: S_task = sum_n psigma_pure[n] * ln(G[n]), G = Gt/w ----
  const float rA0 = __builtin_amdgcn_rcpf(A0);
  float Sp = 0.f;
#pragma unroll
  for (int t = 0; t < 4; ++t)
#pragma unroll
    for (int r = 0; r < 4; ++r) {
      const int n = 16 * t + 4 * g + r;
      if (n < 51) {
        const int i = 4 * t + r;
        const float p  = (ein ? my_sigma[(size_t)ec * 51 + n] : 0.0f) * rA0;
        // guard wC==0 (exact-0 input): p==0 there, force ln arg -> 1
        const float gg = (wC[i] != 0.0f)
                           ? Gt[i] * __builtin_amdgcn_rcpf(wC[i]) : 1.0f;
        Sp += p * __builtin_amdgcn_logf(gg);
      }
    }
  Sp += __shfl_xor(Sp, 16, 64);
  Sp += __shfl_xor(Sp, 32, 64);
  const float St = Sp * 0.69314718056f;
  const float So = __shfl_xor(St, 1, 64);   // partner task's sum

  if (task == 0 && g == 0 && ein) {
    const float lng_resid = A0 * (1.0f / 7.5f) * (So - St);
    const float v0  = v_comp[e];
    const float v1v = v_vt[e];
    const float q0 = A0 * (1.0f / 79.53f), q1 = A1 * (1.0f / 79.53f);
    const float r0 = v0 * (1.0f / 66.69f), r1 = v1v * (1.0f / 66.69f);
    const float xq = 0.235f * q0 + 0.765f * q1;
    const float xr = 0.235f * r0 + 0.765f * r1;
    const float theta = 0.235f * q0 * __builtin_amdgcn_rcpf(xq);
    const float phi   = 0.235f * r0 * __builtin_amdgcn_rcpf(xr);
    const float l0 = 5.0f * (r0 - q0) - (r0 - 1.0f);
    const float l1 = 5.0f * (r1 - q1) - (r1 - 1.0f);
    const float xl = 0.235f * l0 + 0.765f * l1;
    const float lng_comb = fast_log(phi * (1.0f / 0.235f))
                         + 5.0f * q0 * fast_log(theta * __builtin_amdgcn_rcpf(phi))
                         + l0 - (phi * (1.0f / 0.235f)) * xl;
    out[e] = lng_resid + lng_comb;
  }
}

extern "C" void kernel_launch(void* const* d_in, const int* in_sizes, int n_in,
                              void* d_out, int out_size, void* d_ws, size_t ws_size,
                              hipStream_t stream) {
  const float* my  = (const float*)d_in[0];
  const float* vc  = (const float*)d_in[1];
  const float* vts = (const float*)d_in[2];
  const float* vvt = (const float*)d_in[3];
  float* out = (float*)d_out;
  const int B = in_sizes[1];                    // v_compound is [B]
  const int grid = (B + 31) / 32;               // 32 elements per 256-thread block
  cosmo_mfma_stg<<<grid, 256, 0, stream>>>(my, vc, vts, vvt, out, B);
}

// Round 17
// 111.134 us; speedup vs baseline: 1.0761x; 1.0625x over previous
//
#include <hip/hip_runtime.h>

typedef __bf16 bf16;
typedef __attribute__((ext_vector_type(4))) bf16 bf16x4;
typedef __attribute__((ext_vector_type(8))) bf16 bf16x8;
typedef __attribute__((ext_vector_type(4))) float f32x4;

namespace {

constexpr int NITERS = 50;   // R11 ERRATUM: ref's 50-iter iterate is NOT the
                             // fixed point; count must match exactly.

// ---- compile-time physical constants (double) ----
constexpr double csqrt(double x) {
  double s = x > 1 ? x : 1;
  for (int i = 0; i < 60; ++i) s = 0.5 * (s + x / s);
  return s;
}
constexpr double AP_D =
    ((3.667 - 1.0) / (3.667 + 0.5)) * (0.3 * (7.5 * csqrt(7.5)) / 0.0002395);
constexpr double RGAST_D = (8.3144598 / 4184.0) * 623.15;

__device__ __forceinline__ float sss_val(int i, int j) {
  // SSS[i][j] = exp(-DELTAW/(RGAS*T)); symmetric; zero outside 51x51 (pad)
  if (i > 50 || j > 50) return 0.0f;
  const float si = -0.025f + 0.001f * (float)i;
  const float sj = -0.025f + 0.001f * (float)j;
  const float acc = fmaxf(0.0f, fmaxf(si, sj) - 0.0084f);
  const float don = fminf(0.0f, fminf(si, sj) + 0.0084f);
  const float dw = (float)(AP_D * 0.5) * (si + sj) * (si + sj) + 85580.0f * acc * don;
  return expf(-dw * (float)(1.0 / RGAST_D));
}

// Row-slot -> actual sigma-row. Slots 0..47 = rows 0..47. The 3 remaining
// real rows (48,49,50) live in tile-3 class r=0 (slots 48,52,56 = g 0..2);
// ALL of classes (tp=3, r>=1) are pad -> their rcp/fma/cvt instructions are
// skipped wholesale (R17: 13 pad rows were previously smeared across
// instruction classes, wasting ~20% of the quarter-rate rcp budget).
__device__ __forceinline__ int slot2row(int slot) {
  if (slot < 48) return slot;
  if ((slot & 3) == 0 && slot < 60) return 48 + ((slot - 48) >> 2);
  return 99;   // pad -> sss_val 0 / load 0
}

__device__ __forceinline__ float fast_log(float x) {
  return __builtin_amdgcn_logf(x) * 0.69314718056f;   // ln via log2
}

// HW-verified gfx950 shape (guide §3; R4/R5/R8/R9 passed with it).
__device__ __forceinline__ f32x4 mfma(bf16x8 a, bf16x8 b, f32x4 c) {
  return __builtin_amdgcn_mfma_f32_16x16x32_bf16(a, b, c, 0, 0, 0);
}

} // namespace

// One wave = 16 solves (8 elements x {pure, mix}); zero cross-lane movement
// in the hot loop (R9 k-permutation: B-frag position (kt,g,i) <-> row-slot
// 16*(2kt+(i>>2)) + 4g + (i&3) == this lane's own C-layout element).
// State Gt = w (.) G; Gt' = 0.5*(Gt + w*rcp(d)). Tile-3: only element r=0 is
// live (slots 48/52/56 real for g<=2, slot 60 pad via acc-init +1); elements
// r=1..3 are constant 0 -> no rcp/fma/cvt for them. Pads: S rows/cols pad
// are 0; w=0 there -> Gt stays 0.
__global__ __launch_bounds__(256, 4) void cosmo_mfma_trim(
    const float* __restrict__ my_sigma,   // [B,51]
    const float* __restrict__ v_comp,     // [B]
    const float* __restrict__ vt_sigma,   // [B,51,2]
    const float* __restrict__ v_vt,       // [B]
    float* __restrict__ out,              // [B]
    int B)
{
  const int lane = threadIdx.x & 63;
  const int wv   = threadIdx.x >> 6;
  const int s    = lane & 15;     // solve slot (C col / A-frag m pos)
  const int g    = lane >> 4;     // lane group 0..3
  const int e    = blockIdx.x * 32 + wv * 8 + (s >> 1);
  const int task = s & 1;         // 0 = pure, 1 = mix
  const bool ein = (e < B);
  const int  ec  = ein ? e : 0;

  // ---- rows owned by this lane: slot = 16t + 4g + r -> row slot2row ----
  float A0, A1, wC[13];           // 12 live elements tiles 0-2 + 1 (tile3,r0)
  {
    float myv[13], vtv[13];
#pragma unroll
    for (int t = 0; t < 4; ++t)
#pragma unroll
      for (int r = 0; r < 4; ++r) {
        const int li = 4 * t + r;
        if (li >= 13) continue;                  // tile3 r>=1: dead
        const int n  = slot2row(16 * t + 4 * g + r);
        const bool nv = (n < 51) && ein;
        const int nc = (n < 51) ? n : 50;
        myv[li] = nv ? my_sigma[(size_t)ec * 51 + nc] : 0.0f;
        vtv[li] = nv ? vt_sigma[((size_t)ec * 51 + nc) * 2 + 1] : 0.0f;
      }
    float pA0 = 0.f, pA1 = 0.f;
#pragma unroll
    for (int i = 0; i < 13; ++i) { pA0 += myv[i]; pA1 += vtv[i]; }
    A0 = pA0; A0 += __shfl_xor(A0, 16, 64); A0 += __shfl_xor(A0, 32, 64);
    A1 = pA1; A1 += __shfl_xor(A1, 16, 64); A1 += __shfl_xor(A1, 32, 64);

    const float den  = task ? (0.235f * A0 + 0.765f * A1) : A0;
    const float rden = __builtin_amdgcn_rcpf(den);
#pragma unroll
    for (int i = 0; i < 13; ++i) {
      const float num = task ? (0.235f * myv[i] + 0.765f * vtv[i]) : myv[i];
      wC[i] = num * rden;     // psigma of this task; 0 on pads
    }
  }

  float Gt[13];                   // state: Gt = w * G, init G = 1
#pragma unroll
  for (int i = 0; i < 13; ++i) Gt[i] = wC[i];

  // ---- constant A fragments (k-permuted, row-remapped):
  //      afr[tp][kt][i] = S[row(16tp+s)][row(16*(2kt+(i>>2)) + 4g + (i&3))] ----
  bf16x8 afr[4][2];
#pragma unroll
  for (int tp = 0; tp < 4; ++tp)
#pragma unroll
    for (int kt = 0; kt < 2; ++kt) {
      bf16x8 v;
#pragma unroll
      for (int i = 0; i < 8; ++i) {
        const int kslot = 16 * (2 * kt + (i >> 2)) + 4 * g + (i & 3);
        v[i] = (bf16)sss_val(slot2row(16 * tp + s), slot2row(kslot));
      }
      afr[tp][kt] = v;
    }

  // tile-3 acc init: element 0 slot = 48+4g -> pad iff g==3 (+1 -> d=1).
  // Elements 1..3 never read -> init value irrelevant (use 1 to avoid inf).
  f32x4 pad3;
  pad3[0] = (g == 3) ? 1.0f : 0.0f;
  pad3[1] = pad3[2] = pad3[3] = 1.0f;

  const bf16 bz = (bf16)0.0f;

  // ---- 50-step damped fixed point: zero DS ops, zero shuffles ----
#pragma unroll 1
  for (int it = 0; it < NITERS; ++it) {
    bf16x4 hb[4];
#pragma unroll
    for (int t = 0; t < 3; ++t)
#pragma unroll
      for (int r = 0; r < 4; ++r)
        hb[t][r] = (bf16)Gt[4 * t + r];
    hb[3][0] = (bf16)Gt[12];                 // tile3: only r=0 live
    hb[3][1] = bz; hb[3][2] = bz; hb[3][3] = bz;

    const bf16x8 b0 = __builtin_shufflevector(hb[0], hb[1], 0, 1, 2, 3, 4, 5, 6, 7);
    const bf16x8 b1 = __builtin_shufflevector(hb[2], hb[3], 0, 1, 2, 3, 4, 5, 6, 7);

    const f32x4 z = {};
    f32x4 acc[4];
#pragma unroll
    for (int tp = 0; tp < 3; ++tp) acc[tp] = mfma(afr[tp][0], b0, z);
    acc[3] = mfma(afr[3][0], b0, pad3);
#pragma unroll
    for (int tp = 0; tp < 4; ++tp) acc[tp] = mfma(afr[tp][1], b1, acc[tp]);

    // Gt <- 0.5*(Gt + w*rcp(d)) : 12 elements tiles 0-2, + 1 for tile 3
#pragma unroll
    for (int tp = 0; tp < 3; ++tp)
#pragma unroll
      for (int r = 0; r < 4; ++r) {
        const int i = 4 * tp + r;
        const float rc = __builtin_amdgcn_rcpf(acc[tp][r]);
        Gt[i] = 0.5f * __builtin_fmaf(wC[i], rc, Gt[i]);
      }
    {
      const float rc = __builtin_amdgcn_rcpf(acc[3][0]);
      Gt[12] = 0.5f * __builtin_fmaf(wC[12], rc, Gt[12]);
    }
  }

  // ---- epilogue: S_task = sum_n psigma_pure[n] * ln(G[n]), G = Gt/w ----
  const float rA0 = __builtin_amdgcn_rcpf(A0);
  float Sp = 0.f;
#pragma unroll
  for (int t = 0; t < 4; ++t)
#pragma unroll
    for (int r = 0; r < 4; ++r) {
      const int li = 4 * t + r;
      if (li >= 13) continue;
      const int n = slot2row(16 * t + 4 * g + r);
      if (n < 51) {
        const float p  = (ein ? my_sigma[(size_t)ec * 51 + n] : 0.0f) * rA0;
        // guard wC==0 (exact-0 input): p==0 there, force ln arg -> 1
        const float gg = (wC[li] != 0.0f)
                           ? Gt[li] * __builtin_amdgcn_rcpf(wC[li]) : 1.0f;
        Sp += p * __builtin_amdgcn_logf(gg);
      }
    }
  Sp += __shfl_xor(Sp, 16, 64);
  Sp += __shfl_xor(Sp, 32, 64);
  const float St = Sp * 0.69314718056f;
  const float So = __shfl_xor(St, 1, 64);   // partner task's sum

  if (task == 0 && g == 0 && ein) {
    const float lng_resid = A0 * (1.0f / 7.5f) * (So - St);
    const float v0  = v_comp[e];
    const float v1v = v_vt[e];
    const float q0 = A0 * (1.0f / 79.53f), q1 = A1 * (1.0f / 79.53f);
    const float r0 = v0 * (1.0f / 66.69f), r1 = v1v * (1.0f / 66.69f);
    const float xq = 0.235f * q0 + 0.765f * q1;
    const float xr = 0.235f * r0 + 0.765f * r1;
    const float theta = 0.235f * q0 * __builtin_amdgcn_rcpf(xq);
    const float phi   = 0.235f * r0 * __builtin_amdgcn_rcpf(xr);
    const float l0 = 5.0f * (r0 - q0) - (r0 - 1.0f);
    const float l1 = 5.0f * (r1 - q1) - (r1 - 1.0f);
    const float xl = 0.235f * l0 + 0.765f * l1;
    const float lng_comb = fast_log(phi * (1.0f / 0.235f))
                         + 5.0f * q0 * fast_log(theta * __builtin_amdgcn_rcpf(phi))
                         + l0 - (phi * (1.0f / 0.235f)) * xl;
    out[e] = lng_resid + lng_comb;
  }
}

extern "C" void kernel_launch(void* const* d_in, const int* in_sizes, int n_in,
                              void* d_out, int out_size, void* d_ws, size_t ws_size,
                              hipStream_t stream) {
  const float* my  = (const float*)d_in[0];
  const float* vc  = (const float*)d_in[1];
  const float* vts = (const float*)d_in[2];
  const float* vvt = (const float*)d_in[3];
  float* out = (float*)d_out;
  const int B = in_sizes[1];                    // v_compound is [B]
  const int grid = (B + 31) / 32;               // 32 elements per 256-thread block
  cosmo_mfma_trim<<<grid, 256, 0, stream>>>(my, vc, vts, vvt, out, B);
}